// Round 1
// baseline (1325.289 us; speedup 1.0000x reference)
//
#include <hip/hip_runtime.h>
#include <hip/hip_bf16.h>

typedef unsigned short ushort_t;
typedef unsigned int uint_t;

#define BB 16
#define TE 128
#define TD 64
#define HH 256
#define G3 768
#define KK 256
#define OUTV 32000
#define MROWS_E (BB*TE)   // 2048
#define MROWS_D (BB*TD)   // 1024

typedef __attribute__((ext_vector_type(8))) short short8;
typedef __attribute__((ext_vector_type(4))) float f32x4;

__device__ __forceinline__ float b2f(ushort_t u) {
  union { uint_t i; float f; } v; v.i = ((uint_t)u) << 16; return v.f;
}
__device__ __forceinline__ ushort_t f2b(float f) {
  union { float f; uint_t i; } v; v.f = f;
  uint_t x = v.i;
  return (ushort_t)((x + 0x7fffu + ((x >> 16) & 1u)) >> 16);
}
// dtype-adaptive scalar load of a "float" input: f32f!=0 -> fp32 buffer, else bf16
__device__ __forceinline__ float ldf(const void* p, size_t i, uint_t f32f) {
  return f32f ? ((const float*)p)[i] : b2f(((const ushort_t*)p)[i]);
}
// fast, saturating sigmoid/tanh (inputs bounded; formulas robust at +-inf)
__device__ __forceinline__ float fsig(float x) { return 1.f/(1.f + __expf(-x)); }
__device__ __forceinline__ float ftanh(float x) { return 1.f - 2.f/(__expf(2.f*x) + 1.f); }

// async global->LDS, 16B per lane. Dest must be contiguous in lane order.
__device__ __forceinline__ void gload_lds16(const void* g, void* l) {
  __builtin_amdgcn_global_load_lds(
      (const __attribute__((address_space(1))) unsigned int*)g,
      (__attribute__((address_space(3))) unsigned int*)l, 16, 0, 0);
}

// ---------------------------------------------------------------------------
// dtype detector (fp32 on this harness; kept for safety).
// ---------------------------------------------------------------------------
__global__ __launch_bounds__(256) void detect_kernel(const void* emb, uint_t* flag) {
  int tid = threadIdx.x;
  uint_t w = ((const uint_t*)emb)[tid];
  uint_t e = (w >> 7) & 0xFFu;
  bool pass = (e >= 100u && e <= 127u);
  unsigned long long m = __ballot(pass);
  __shared__ int cnt[4];
  if ((tid & 63) == 0) cnt[tid >> 6] = __popcll(m);
  __syncthreads();
  if (tid == 0) {
    int c = cnt[0] + cnt[1] + cnt[2] + cnt[3];
    *flag = (c >= 128) ? 0u : 1u;
  }
}

// ---------------------------------------------------------------------------
// prep: Whh -> bf16 [768][256]; dense_W -> bf16 transpose; combined gi biases
// (bih + bhh folded for r,z gates -> GRU needn't add them); out bias -> fp32.
// ---------------------------------------------------------------------------
__global__ __launch_bounds__(256) void prep_kernel(
    const void* eWhh, const void* dWhh, const void* denseW,
    const void* ebih, const void* ebhh, const void* dbih, const void* dbhh,
    const void* outb, const uint_t* flagp,
    ushort_t* WBe, ushort_t* WBd, ushort_t* DWT,
    float* cbe, float* cbd, float* obf) {
  uint_t f = *flagp;
  int tid = blockIdx.x * blockDim.x + threadIdx.x;
  int nth = gridDim.x * blockDim.x;
  for (int i = tid; i < G3*KK; i += nth) {
    WBe[i] = f2b(ldf(eWhh, i, f));
    WBd[i] = f2b(ldf(dWhh, i, f));
  }
  for (int i = tid; i < 512*HH; i += nth) {
    int k = i / HH, c = i % HH;
    DWT[i] = f2b(ldf(denseW, (size_t)c*512 + k, f));
  }
  for (int i = tid; i < G3; i += nth) {
    float be = ldf(ebih, i, f), bd = ldf(dbih, i, f);
    if (i < 2*HH) { be += ldf(ebhh, i, f); bd += ldf(dbhh, i, f); }
    cbe[i] = be; cbd[i] = bd;
  }
  for (int i = tid; i < OUTV; i += nth) obf[i] = ldf(outb, i, f);
}

// ---------------------------------------------------------------------------
// Generic MFMA GEMM: C[m][n] = sum_k A[m][k]*B[n][k] (+bias[n]), K=256 fixed.
// tshift!=0: output rows remapped m=(b*T+t) -> t*BB+b with T=1<<tshift.
// a_f32!=0: ws A operand is fp32 (converted to bf16 during staging).
// bias (if non-null) is always fp32 (prep-produced).
// ---------------------------------------------------------------------------
#define LDT 264

__global__ __launch_bounds__(256) void gemm_kernel(
    const ushort_t* A, const int* tokens, const void* emb,
    const void* Bw, int ldb, int b_off,
    const float* bias, const uint_t* flagp,
    float* Cf, ushort_t* Cb, int ldc, int M, int tshift, int a_f32) {
  __shared__ __align__(16) ushort_t Bs[64*LDT];
  __shared__ __align__(16) ushort_t As[32*LDT];
  uint_t f = *flagp;
  int tid = threadIdx.x;
  int wave = tid >> 6, lane = tid & 63;
  int n0 = blockIdx.x * 64;
#pragma unroll
  for (int it = 0; it < 8; ++it) {
    int idx = it*256 + tid;
    int row = idx >> 5, col = (idx & 31) << 3;
    size_t e = (size_t)(n0 + row)*ldb + col + b_off;
    uint4 v;
    if (f) {
      const float4* s = (const float4*)((const float*)Bw + e);
      float4 x = s[0], y = s[1];
      v.x = (uint_t)f2b(x.x) | ((uint_t)f2b(x.y) << 16);
      v.y = (uint_t)f2b(x.z) | ((uint_t)f2b(x.w) << 16);
      v.z = (uint_t)f2b(y.x) | ((uint_t)f2b(y.y) << 16);
      v.w = (uint_t)f2b(y.z) | ((uint_t)f2b(y.w) << 16);
    } else {
      v = *(const uint4*)((const ushort_t*)Bw + e);
    }
    *(uint4*)(Bs + row*LDT + col) = v;
  }
  int arow_i = lane & 15;
  float bias_v = 0.f;
  if (bias) bias_v = bias[n0 + wave*16 + arow_i];
  int koff = (lane >> 4) << 3;
  for (int m0 = blockIdx.y*32; m0 < M; m0 += gridDim.y*32) {
    __syncthreads();   // Bs ready / previous chunk compute done
#pragma unroll
    for (int it = 0; it < 4; ++it) {
      int idx = it*256 + tid;
      int row = idx >> 5, col = (idx & 31) << 3;
      uint4 v;
      if (tokens) {
        size_t e = (size_t)tokens[m0 + row]*KK + col;
        if (f) {
          const float4* s = (const float4*)((const float*)emb + e);
          float4 x = s[0], y = s[1];
          v.x = (uint_t)f2b(x.x) | ((uint_t)f2b(x.y) << 16);
          v.y = (uint_t)f2b(x.z) | ((uint_t)f2b(x.w) << 16);
          v.z = (uint_t)f2b(y.x) | ((uint_t)f2b(y.y) << 16);
          v.w = (uint_t)f2b(y.z) | ((uint_t)f2b(y.w) << 16);
        } else {
          v = *(const uint4*)((const ushort_t*)emb + e);
        }
      } else if (a_f32) {
        const float4* s = (const float4*)((const float*)A + (size_t)(m0 + row)*KK + col);
        float4 x = s[0], y = s[1];
        v.x = (uint_t)f2b(x.x) | ((uint_t)f2b(x.y) << 16);
        v.y = (uint_t)f2b(x.z) | ((uint_t)f2b(x.w) << 16);
        v.z = (uint_t)f2b(y.x) | ((uint_t)f2b(y.y) << 16);
        v.w = (uint_t)f2b(y.z) | ((uint_t)f2b(y.w) << 16);
      } else {
        v = *(const uint4*)(A + (size_t)(m0 + row)*KK + col);  // ws bf16
      }
      *(uint4*)(As + row*LDT + col) = v;
    }
    __syncthreads();
#pragma unroll
    for (int msub = 0; msub < 2; ++msub) {
      f32x4 acc = {0.f,0.f,0.f,0.f};
      const ushort_t* ap = As + (msub*16 + arow_i)*LDT + koff;
      const ushort_t* bp = Bs + (wave*16 + arow_i)*LDT + koff;
#pragma unroll
      for (int ks = 0; ks < 8; ++ks) {
        short8 af = *(const short8*)(ap + ks*32);
        short8 bf = *(const short8*)(bp + ks*32);
        acc = __builtin_amdgcn_mfma_f32_16x16x32_bf16(af, bf, acc, 0, 0, 0);
      }
      int mbase = m0 + msub*16 + (lane >> 4)*4;
      int ncol = n0 + wave*16 + arow_i;
#pragma unroll
      for (int r = 0; r < 4; ++r) {
        float val = acc[r] + bias_v;
        int mr = mbase + r;
        int orow = tshift ? (((mr & ((1 << tshift) - 1)) << 4) + (mr >> tshift)) : mr;
        if (Cf) Cf[(size_t)orow*ldc + ncol] = val;
        else    Cb[(size_t)orow*ldc + ncol] = f2b(val);
      }
    }
  }
}

// ---------------------------------------------------------------------------
// MFMA GRU: ONE block, 512 threads (8 waves, 2 waves/SIMD -> 256-reg cap on
// the unified VGPR/AGPR file).
//
// ROUND-0 THEORY: previous version's bfrag (192 regs) + acc(24) + 64-bit
// store addressing exceeded 256 -> compiler rematerialized Whh loads inside
// the t-loop -> ~384KB/step re-streamed from L2 -> 4.1us/step. This version:
//   * MFMA split into two per-tt passes (acc 24 -> 12)
//   * bfrag pinned via empty asm (remat impossible)
//   * bhh(r,z) folded into gi bias at prep; out_bf stores removed
//     (eprj/dprj GEMMs convert fp32->bf16 in their own staging)
//   * 32-bit lane-const out index base; all LDS gi reads use imm offsets
// Non-bfrag peak ~55 regs -> fragments stay resident.
// ---------------------------------------------------------------------------
#define HSBF 264            // h_bf row stride (bf16)
#define HBUF (BB*HSBF)      // 4224 shorts = 8448 B per buffer
#define GILDS 772           // gi row stride (fp32)
#define GIBUF (BB*GILDS)    // 12352 floats = 49408 B per buffer

__device__ __forceinline__ void stage_gi(const float* gi, int t, float* sbuf,
                                         int wave, int lane) {
#pragma unroll
  for (int rr = 0; rr < 2; ++rr) {
    int m = wave*2 + rr;
    const float* src = gi + ((size_t)t*BB + m)*G3 + lane*4;
    float* dst = sbuf + m*GILDS + lane*4;
#pragma unroll
    for (int rd = 0; rd < 3; ++rd)
      gload_lds16(src + rd*256, dst + rd*256);
  }
}

__device__ __forceinline__ void gru_phase(
    const float* gi, const ushort_t* WB, const void* bhh, const int* lens,
    uint_t f, const int T, float* out,
    float* gi_lds, ushort_t* h_bf, float (&hreg)[8], bool init_h)
{
  int tid = threadIdx.x;
  int wave = tid >> 6, lane = tid & 63;
  int mrow = lane & 15, quad = lane >> 4;
  // register-resident Whh fragments: gate g, tile tt -> rows g*256+32w+16tt+mrow
  short8 bfrag[3][2][8];
#pragma unroll
  for (int g = 0; g < 3; ++g)
#pragma unroll
    for (int tt = 0; tt < 2; ++tt) {
      const ushort_t* wb = WB + (size_t)(g*HH + wave*32 + tt*16 + mrow)*KK + (quad << 3);
#pragma unroll
      for (int ks = 0; ks < 8; ++ks)
        bfrag[g][tt][ks] = *(const short8*)(wb + ks*32);
    }
  // Pin: asm-defined values cannot be rematerialized as loads in the loop.
#define PIN8(A) asm volatile("" : "+v"(A[0]), "+v"(A[1]), "+v"(A[2]), "+v"(A[3]), \
                                  "+v"(A[4]), "+v"(A[5]), "+v"(A[6]), "+v"(A[7]))
  PIN8(bfrag[0][0]); PIN8(bfrag[0][1]);
  PIN8(bfrag[1][0]); PIN8(bfrag[1][1]);
  PIN8(bfrag[2][0]); PIN8(bfrag[2][1]);
#undef PIN8
  // only the n-gate hidden bias is applied in-kernel (r,z folded into gi)
  float bias_n[2];
#pragma unroll
  for (int tt = 0; tt < 2; ++tt)
    bias_n[tt] = ldf(bhh, 2*HH + wave*32 + tt*16 + mrow, f);
  int len_r[4];
#pragma unroll
  for (int r = 0; r < 4; ++r) len_r[r] = lens[quad*4 + r];
  const int obase = (quad*4*T)*HH + wave*32 + mrow;   // 32-bit out index base
  if (init_h) {
#pragma unroll
    for (int i = 0; i < 8; ++i) hreg[i] = 0.f;
    for (int i = tid; i < HBUF; i += 512) h_bf[i] = 0;   // buffer 0 only
  }
  stage_gi(gi, 0, gi_lds, wave, lane);
  __syncthreads();   // h_bf[0] + gi buf[0] ready (vmcnt drained by barrier)
  for (int t = 0; t < T; ++t) {
    const float* gbuf = gi_lds + (t & 1)*GIBUF;
    float* sbuf = gi_lds + ((t + 1) & 1)*GIBUF;
    const ushort_t* hb_r = h_bf + (t & 1)*HBUF;
    ushort_t* hb_w = h_bf + ((t + 1) & 1)*HBUF;
    if (t + 1 < T) stage_gi(gi, t + 1, sbuf, wave, lane);
    const ushort_t* hb = hb_r + mrow*HSBF + (quad << 3);
#pragma unroll
    for (int tt = 0; tt < 2; ++tt) {
      f32x4 accr = {0.f,0.f,0.f,0.f};
      f32x4 accz = {0.f,0.f,0.f,0.f};
      f32x4 accn = {0.f,0.f,0.f,0.f};
#pragma unroll
      for (int ks = 0; ks < 8; ++ks) {
        short8 av = *(const short8*)(hb + ks*32);
        accr = __builtin_amdgcn_mfma_f32_16x16x32_bf16(av, bfrag[0][tt][ks], accr, 0, 0, 0);
        accz = __builtin_amdgcn_mfma_f32_16x16x32_bf16(av, bfrag[1][tt][ks], accz, 0, 0, 0);
        accn = __builtin_amdgcn_mfma_f32_16x16x32_bf16(av, bfrag[2][tt][ks], accn, 0, 0, 0);
      }
      const float* gp = gbuf + quad*4*GILDS + wave*32 + tt*16 + mrow;
      float bn = bias_n[tt];
#pragma unroll
      for (int r = 0; r < 4; ++r) {
        float rr = fsig(gp[r*GILDS]          + accr[r]);   // bih+bhh already in gi
        float zz = fsig(gp[r*GILDS +   HH]   + accz[r]);
        float nn = ftanh(gp[r*GILDS + 2*HH] + rr*(accn[r] + bn));
        float hold = hreg[tt*4 + r];
        float hc = (1.f - zz)*nn + zz*hold;
        bool valid = t < len_r[r];
        float ov = valid ? hc : 0.f;
        float hnew = valid ? hc : hold;
        out[obase + r*(T*HH) + t*HH + tt*16] = ov;
        hreg[tt*4 + r] = hnew;
        hb_w[quad*4*HSBF + r*HSBF + wave*32 + tt*16 + mrow] = f2b(hnew);
      }
    }
    __syncthreads();   // h_bf[1-p] + gi buf for t+1 ready for next step
  }
}

__global__ __launch_bounds__(512, 2) void gru_kernel(
    const float* gi_e, const float* gi_d, const ushort_t* WBe, const ushort_t* WBd,
    const void* ebhh, const void* dbhh, const uint_t* flagp,
    const int* elen, const int* dlen, float* eout, float* dout) {
  uint_t f = *flagp;
  __shared__ __align__(16) float gi_lds[2*GIBUF];    // 98816 B
  __shared__ __align__(16) ushort_t h_bf[2*HBUF];    // 16896 B
  float hreg[8];
  gru_phase(gi_e, WBe, ebhh, elen, f, TE, eout, gi_lds, h_bf, hreg, true);
  // TE=128 even -> encoder's final h landed in h_bf buffer 0; decoder reads it.
  gru_phase(gi_d, WBd, dbhh, dlen, f, TD, dout, gi_lds, h_bf, hreg, false);
}

// ---------------------------------------------------------------------------
// Attention + dense, one block per (b, td). (unchanged)
// ---------------------------------------------------------------------------
__global__ __launch_bounds__(256) void attn_kernel(
    const float* eprj, const float* dprj, const float* eout, const float* dout,
    const void* Wb, const void* av, const void* avb,
    const ushort_t* DWT, const void* db, const uint_t* flagp,
    const int* elen, const int* dlen, ushort_t* dense_bf) {
  int bd = blockIdx.x;
  int b = bd / TD, td = bd % TD;
  int tid = threadIdx.x;
  int wave = tid >> 6, lane = tid & 63;
  uint_t f = *flagp;
  __shared__ float dp[HH], dsrow[HH], vv[HH], att[TE];
  int el = elen[b];
  bool dok = td < dlen[b];
  size_t drow = (size_t)bd * HH;
  dp[tid] = dprj[drow + tid] + ldf(Wb, tid, f);
  dsrow[tid] = dout[drow + tid];
  vv[tid] = ldf(av, tid, f);
  __syncthreads();
  float vb0 = ldf(avb, 0, f);
  for (int teb = 0; teb < TE/4; ++teb) {
    int te = teb*4 + wave;
    float e = -1e30f;
    if (dok && te < el) {
      const float* ep = eprj + (size_t)(b*TE + te)*HH;
      float s = 0.f;
#pragma unroll
      for (int i = 0; i < 4; ++i) {
        int hh = lane + 64*i;
        s += tanhf(ep[hh] + dp[hh]) * vv[hh];
      }
#pragma unroll
      for (int off = 32; off > 0; off >>= 1) s += __shfl_xor(s, off);
      e = s + vb0;
    }
    if (lane == 0) att[te] = e;
  }
  __syncthreads();
  float m = -1e30f;
  for (int te = 0; te < TE; ++te) m = fmaxf(m, att[te]);
  __syncthreads();
  if (tid < TE) {
    float e = att[tid];
    att[tid] = (e > -1e29f) ? expf(e - m) : 0.f;
  }
  __syncthreads();
  float ssum = 0.f;
  for (int te = 0; te < TE; ++te) ssum += att[te];
  float inv = (ssum > 0.f) ? 1.f/ssum : 0.f;
  float c = 0.f;
  for (int te = 0; te < TE; ++te) {
    float wgt = att[te];
    if (wgt > 0.f) c += wgt * eout[(size_t)(b*TE + te)*HH + tid];
  }
  c *= inv;
  __syncthreads();
  dp[tid] = c;   // reuse dp as context
  __syncthreads();
  float acc = ldf(db, tid, f);
#pragma unroll 4
  for (int k = 0; k < HH; ++k) acc = fmaf(b2f(DWT[k*HH + tid]), dsrow[k], acc);
#pragma unroll 4
  for (int k = 0; k < HH; ++k) acc = fmaf(b2f(DWT[(HH + k)*HH + tid]), dp[k], acc);
  dense_bf[drow + tid] = f2b(tanhf(acc));
}

// ---------------------------------------------------------------------------
extern "C" void kernel_launch(void* const* d_in, const int* in_sizes, int n_in,
                              void* d_out, int out_size, void* d_ws, size_t ws_size,
                              hipStream_t stream) {
  const int* enc_in   = (const int*)d_in[0];
  const int* enc_len  = (const int*)d_in[1];
  const int* dec_in   = (const int*)d_in[2];
  const int* dec_len  = (const int*)d_in[3];
  const void* emb    = d_in[4];
  const void* eWih   = d_in[5];
  const void* eWhh   = d_in[6];
  const void* ebih   = d_in[7];
  const void* ebhh   = d_in[8];
  const void* dWih   = d_in[9];
  const void* dWhh   = d_in[10];
  const void* dbih   = d_in[11];
  const void* dbhh   = d_in[12];
  const void* attnW  = d_in[13];
  const void* attnWb = d_in[14];
  const void* attnv  = d_in[15];
  const void* attnvb = d_in[16];
  const void* denseW = d_in[17];
  const void* denseb = d_in[18];
  const void* outW   = d_in[19];
  const void* outb   = d_in[20];
  float* out = (float*)d_out;   // reference output is fp32

  float* ws = (float*)d_ws;
  size_t o = 0;
  uint_t* flag = (uint_t*)(ws + o);   o += 4;
  ushort_t* WBe = (ushort_t*)(ws + o); o += G3*KK/2;
  ushort_t* WBd = (ushort_t*)(ws + o); o += G3*KK/2;
  ushort_t* DWT = (ushort_t*)(ws + o); o += 512*HH/2;
  float* cbe = ws + o;                o += G3;
  float* cbd = ws + o;                o += G3;
  float* obf = ws + o;                o += OUTV;
  float* gi_e = ws + o;               o += (size_t)MROWS_E*G3;   // (t,b)-interleaved
  float* gi_d = ws + o;               o += (size_t)MROWS_D*G3;   // (t,b)-interleaved
  float* eout = ws + o;               o += (size_t)MROWS_E*HH;
  float* dout = ws + o;               o += (size_t)MROWS_D*HH;
  float* eprj = ws + o;               o += (size_t)MROWS_E*HH;
  float* dprj = ws + o;               o += (size_t)MROWS_D*HH;
  ushort_t* dense_bf = (ushort_t*)(ws + o); o += (size_t)MROWS_D*HH/2;

  detect_kernel<<<1, 256, 0, stream>>>(emb, flag);
  prep_kernel<<<384, 256, 0, stream>>>(eWhh, dWhh, denseW, ebih, ebhh, dbih, dbhh,
                                       outb, flag, WBe, WBd, DWT, cbe, cbd, obf);
  // gi = emb[tokens] @ Wih.T + (bih + bhh[r,z]), rows (t,b)-interleaved
  gemm_kernel<<<dim3(12,8), 256, 0, stream>>>(nullptr, enc_in, emb, eWih, 256, 0,
                                              cbe, flag, gi_e, nullptr, G3, MROWS_E, 7, 0);
  gemm_kernel<<<dim3(12,4), 256, 0, stream>>>(nullptr, dec_in, emb, dWih, 256, 0,
                                              cbd, flag, gi_d, nullptr, G3, MROWS_D, 6, 0);
  gru_kernel<<<1, 512, 0, stream>>>(gi_e, gi_d, WBe, WBd, ebhh, dbhh, flag,
                                    enc_len, dec_len, eout, dout);
  // enc_proj = enc_out @ W1.T ; dec_proj = dec_out @ W2.T  (attn_W col split)
  gemm_kernel<<<dim3(4,16), 256, 0, stream>>>((const ushort_t*)eout, nullptr, nullptr,
                                              attnW, 512, 0, nullptr, flag, eprj,
                                              nullptr, HH, MROWS_E, 0, 1);
  gemm_kernel<<<dim3(4,8), 256, 0, stream>>>((const ushort_t*)dout, nullptr, nullptr,
                                             attnW, 512, 256, nullptr, flag, dprj,
                                             nullptr, HH, MROWS_D, 0, 1);
  attn_kernel<<<MROWS_D, 256, 0, stream>>>(eprj, dprj, eout, dout, attnWb, attnv, attnvb,
                                           DWT, denseb, flag, enc_len, dec_len, dense_bf);
  // logits = dense @ out_W.T + out_b  (fp32 out)
  gemm_kernel<<<dim3(500,4), 256, 0, stream>>>(dense_bf, nullptr, nullptr, outW, 256, 0,
                                               obf, flag, out, nullptr, OUTV, MROWS_D, 0, 0);
}